// Round 12
// baseline (109.314 us; speedup 1.0000x reference)
//
#include <hip/hip_runtime.h>
#include <math.h>
#include <stdint.h>

#define B_ 2
#define N_ 2048
#define D_ 1024
#define H_ 16
#define HD_ 64
#define M_ (B_ * N_)   // 4096

typedef __bf16 bf16x8 __attribute__((ext_vector_type(8)));
typedef float f32x4 __attribute__((ext_vector_type(4)));

__device__ __forceinline__ ushort bfbits(float f) {
    __bf16 h = (__bf16)f;
    return __builtin_bit_cast(ushort, h);
}

// async global->LDS, 16B per lane; LDS dest = wave-uniform base + lane*16
__device__ __forceinline__ void glds16(const ushort* g, ushort* l) {
    __builtin_amdgcn_global_load_lds(
        (const __attribute__((address_space(1))) uint32_t*)g,
        (__attribute__((address_space(3))) uint32_t*)l, 16, 0, 0);
}

// ---------------------------------------------------------------------------
// Prep: cvt_x (blocks 0..4095) + cvt_w transpose (blocks 4096..8191).
// ---------------------------------------------------------------------------
__global__ __launch_bounds__(256) void prep(const float* __restrict__ x,
                                            const float* __restrict__ W0,
                                            const float* __restrict__ W1,
                                            const float* __restrict__ W2,
                                            const float* __restrict__ W3,
                                            ushort* __restrict__ xb,
                                            ushort* __restrict__ Wt) {
    __shared__ float T[32][33];
    const int t = threadIdx.x;
    int id = blockIdx.x;
    if (id < 4096) {
        int i = id * 256 + t;
        float4 v = ((const float4*)x)[i];
        ushort4 o;
        o.x = bfbits(v.x); o.y = bfbits(v.y); o.z = bfbits(v.z); o.w = bfbits(v.w);
        ((ushort4*)xb)[i] = o;
        return;
    }
    id -= 4096;
    const int z = id >> 10;
    const int k0 = (id & 31) * 32, n0 = ((id >> 5) & 31) * 32;
    const float* W = (z == 0) ? W0 : (z == 1) ? W1 : (z == 2) ? W2 : W3;
    ushort* out = Wt + (size_t)z * D_ * D_;
    {
        int kl = t >> 3, nl = (t & 7) * 4;
        float4 v = *(const float4*)&W[(size_t)(k0 + kl) * D_ + n0 + nl];
        T[kl][nl] = v.x; T[kl][nl + 1] = v.y; T[kl][nl + 2] = v.z; T[kl][nl + 3] = v.w;
    }
    __syncthreads();
    {
        int nl = t >> 3, k4 = (t & 7) * 4;
        ushort4 o;
        o.x = bfbits(T[k4 + 0][nl]); o.y = bfbits(T[k4 + 1][nl]);
        o.z = bfbits(T[k4 + 2][nl]); o.w = bfbits(T[k4 + 3][nl]);
        *(ushort4*)&out[(size_t)(n0 + nl) * D_ + k0 + k4] = o;
    }
}

// ---------------------------------------------------------------------------
// QKV projection, 8-phase 256x256 schedule (m201-style), 512 threads = 8
// waves (2 Mx4 N).  BK=64, 2 K-tiles/iter, LDS = 2buf x (A[256][64] +
// B[256][64]) = 128KB.  Counted vmcnt(4) at phases 0/4 only (loads span
// barriers); drain vmcnt(0) only at last-iter p4.  slot^(row&7) both-sides
// swizzle; raw s_barrier + sched_barrier fencing; setprio around MFMA.
//
// Stage schedule (derived; margins >= 2 phases, all reads covered):
//   p0: A1h1(this)   p1: B1h0(this)  p2: B1h1(this)  p3: A0h0(next)
//   p4: A0h1(next)   p5: B0h0(next)  p6: B0h1(next)  p7: A1h0(next)
// consume: buf0 @ p0-3 (A-h0 p0/1, A-h1 p2/3, B all), buf1 @ p4-7.
// vmcnt(4)@p0 covers through prev-p6; vmcnt(4)@p4 covers through p2.
// p0/p4 issue their ds_reads AFTER the barrier (their data is only then
// guaranteed); other phases read pre-barrier (covered by p0/p4 waits).
//
// op 0/1 (Q,K): C = xb[M][K] * Wt^T -> row-major [M][D] (Q scaled).
// op 2   (V):   C = Wv^T[d][k] * xb^T -> directly [b*1024+d][N] (= attn's
//               transposed-V layout), coalesced li-contiguous stores.
// grid 192 flat (8|192 -> bijective XCD swizzle).
// ---------------------------------------------------------------------------
#define QSCALE 0.180336880f   // 1/sqrt(64) * log2(e)

#define STG(SRC, RB, K0, DST, HALF)                                            \
    do {                                                                       \
        glds16(&SRC[(size_t)((RB) + (HALF) * 128 + w * 8 + r8) * 1024 + (K0) + s8], \
               &DST[((HALF) * 128 + w * 8) * 64]);                             \
        glds16(&SRC[(size_t)((RB) + (HALF) * 128 + (w + 8) * 8 + r8) * 1024 + (K0) + s8], \
               &DST[((HALF) * 128 + (w + 8) * 8) * 64]);                       \
    } while (0)

#define DS_READS(KT, MH, TK)                                                   \
    _Pragma("unroll") for (int mi = 0; mi < 4; ++mi)                           \
        af[mi] = *(const bf16x8*)&LA[KT][(wr * 128 + ((MH) * 4 + mi) * 16 + li) * 64 + \
                                         ((((TK) * 4 + lg) ^ rsw) << 3)];      \
    _Pragma("unroll") for (int nj = 0; nj < 4; ++nj)                           \
        bfr[nj] = *(const bf16x8*)&LB[KT][(wc * 64 + nj * 16 + li) * 64 +      \
                                          ((((TK) * 4 + lg) ^ rsw) << 3)];

#define MFMA16(MH)                                                             \
    __builtin_amdgcn_s_setprio(1);                                             \
    _Pragma("unroll") for (int mi = 0; mi < 4; ++mi)                           \
        _Pragma("unroll") for (int nj = 0; nj < 4; ++nj)                       \
            acc[(MH) * 4 + mi][nj] = __builtin_amdgcn_mfma_f32_16x16x32_bf16(  \
                af[mi], bfr[nj], acc[(MH) * 4 + mi][nj], 0, 0, 0);             \
    __builtin_amdgcn_s_setprio(0);

#define BARF()                                                                 \
    __builtin_amdgcn_sched_barrier(0);                                         \
    __builtin_amdgcn_s_barrier();                                              \
    __builtin_amdgcn_sched_barrier(0)

__global__ __launch_bounds__(512, 2) void qkv8_gemm(const ushort* __restrict__ xb,
                                                    const ushort* __restrict__ Wt,
                                                    ushort* __restrict__ q,
                                                    ushort* __restrict__ k,
                                                    ushort* __restrict__ vt) {
    __shared__ ushort LA[2][256 * 64];
    __shared__ ushort LB[2][256 * 64];

    const int t = threadIdx.x;
    const int l = t & 63;
    const int w = __builtin_amdgcn_readfirstlane(t >> 6);   // 0..7
    const int wr = w >> 2, wc = w & 3;
    const int li = l & 15, lg = l >> 4;
    const int r8 = l >> 3;
    const int s8 = ((l & 7) ^ r8) * 8;      // inverse-swizzled source slot
    const int rsw = li & 7;                 // read-side row xor

    const int wg = (blockIdx.x & 7) * 24 + (blockIdx.x >> 3);  // XCD swizzle
    const int op = wg >> 6;                 // 0:Q 1:K 2:V
    const int rr_ = wg & 63;
    const ushort* Asrc; const ushort* Bsrc;
    int rowbase, colbase;
    if (op < 2) {
        Asrc = xb; Bsrc = Wt + (size_t)op * D_ * D_;
        rowbase = (rr_ & 15) * 256;          // token rows
        colbase = (rr_ >> 4) * 256;          // D cols (0..768)
    } else {
        Asrc = Wt + (size_t)2 * D_ * D_;     // Wv^T rows = d
        Bsrc = xb;                           // rows = tokens
        rowbase = (rr_ & 3) * 256;           // d rows
        colbase = (rr_ >> 2) * 256;          // token cols
    }

    f32x4 acc[8][4];
    #pragma unroll
    for (int m = 0; m < 8; ++m)
        #pragma unroll
        for (int n = 0; n < 4; ++n)
            acc[m][n] = (f32x4){0.f, 0.f, 0.f, 0.f};

    // prologue: stage both K-tiles of iteration 0
    STG(Asrc, rowbase, 0, LA[0], 0);  STG(Asrc, rowbase, 0, LA[0], 1);
    STG(Bsrc, colbase, 0, LB[0], 0);  STG(Bsrc, colbase, 0, LB[0], 1);
    STG(Asrc, rowbase, 64, LA[1], 0); STG(Asrc, rowbase, 64, LA[1], 1);
    STG(Bsrc, colbase, 64, LB[1], 0); STG(Bsrc, colbase, 64, LB[1], 1);

    #pragma unroll 1
    for (int it = 0; it < 8; ++it) {
        const int kT1 = it * 128 + 64;       // this iter kt1
        const int kN0 = it * 128 + 128;      // next iter kt0
        const int kN1 = it * 128 + 192;      // next iter kt1
        bf16x8 af[4], bfr[4];

        // p0 (kt0, mh0, tk0): stage A1h1(this); vmcnt(4); reads AFTER barrier
        if (it > 0) STG(Asrc, rowbase, kT1, LA[1], 1);
        asm volatile("s_waitcnt vmcnt(4)" ::: "memory");
        BARF();
        DS_READS(0, 0, 0);
        MFMA16(0);
        BARF();
        // p1 (kt0, mh0, tk1): stage B1h0(this)
        DS_READS(0, 0, 1);
        if (it > 0) STG(Bsrc, colbase, kT1, LB[1], 0);
        BARF();
        MFMA16(0);
        BARF();
        // p2 (kt0, mh1, tk0): stage B1h1(this)
        DS_READS(0, 1, 0);
        if (it > 0) STG(Bsrc, colbase, kT1, LB[1], 1);
        BARF();
        MFMA16(1);
        BARF();
        // p3 (kt0, mh1, tk1): stage A0h0(next)
        DS_READS(0, 1, 1);
        if (it < 7) STG(Asrc, rowbase, kN0, LA[0], 0);
        BARF();
        MFMA16(1);
        BARF();
        // p4 (kt1, mh0, tk0): stage A0h1(next); vmcnt; reads AFTER barrier
        if (it < 7) {
            STG(Asrc, rowbase, kN0, LA[0], 1);
            asm volatile("s_waitcnt vmcnt(4)" ::: "memory");
        } else {
            asm volatile("s_waitcnt vmcnt(0)" ::: "memory");
        }
        BARF();
        DS_READS(1, 0, 0);
        MFMA16(0);
        BARF();
        // p5 (kt1, mh0, tk1): stage B0h0(next)
        DS_READS(1, 0, 1);
        if (it < 7) STG(Bsrc, colbase, kN0, LB[0], 0);
        BARF();
        MFMA16(0);
        BARF();
        // p6 (kt1, mh1, tk0): stage B0h1(next)
        DS_READS(1, 1, 0);
        if (it < 7) STG(Bsrc, colbase, kN0, LB[0], 1);
        BARF();
        MFMA16(1);
        BARF();
        // p7 (kt1, mh1, tk1): stage A1h0(next)
        DS_READS(1, 1, 1);
        if (it < 7) STG(Asrc, rowbase, kN1, LA[1], 0);
        BARF();
        MFMA16(1);
        BARF();
    }

    // epilogue: direct stores (li-contiguous bf16 -> 32B-coalesced groups)
    if (op < 2) {
        ushort* out = (op == 0) ? q : k;
        const float scale = (op == 0) ? QSCALE : 1.0f;
        #pragma unroll
        for (int m = 0; m < 8; ++m)
            #pragma unroll
            for (int n = 0; n < 4; ++n)
                #pragma unroll
                for (int r = 0; r < 4; ++r) {
                    const int grow = rowbase + wr * 128 + m * 16 + lg * 4 + r;
                    const int gcol = colbase + wc * 64 + n * 16 + li;
                    out[(size_t)grow * D_ + gcol] = bfbits(acc[m][n][r] * scale);
                }
    } else {
        const int bb = colbase >> 11;        // batch (token tile never spans)
        const int tcb = colbase & (N_ - 1);
        #pragma unroll
        for (int m = 0; m < 8; ++m)
            #pragma unroll
            for (int n = 0; n < 4; ++n)
                #pragma unroll
                for (int r = 0; r < 4; ++r) {
                    const int drow = rowbase + wr * 128 + m * 16 + lg * 4 + r;
                    const int tcol = tcb + wc * 64 + n * 16 + li;
                    vt[((size_t)(bb * 1024 + drow)) * N_ + tcol] = bfbits(acc[m][n][r]);
                }
    }
}

// ---------------------------------------------------------------------------
// MFMA GEMM mainloop (m97 structure): 128x128 tile, BK=32, linear LDS
// [128][32] bf16 staged via global_load_lds w=16, both-sides XOR swizzle.
// (kept for out_gemm)
// ---------------------------------------------------------------------------
#define BK 32

__device__ __forceinline__ void gemm_tile(const ushort* __restrict__ A,
                                          const ushort* __restrict__ Bt,
                                          int K, int tileM, int tileN,
                                          ushort* As, ushort* Bs,
                                          f32x4 acc[4][4]) {
    const int t = threadIdx.x;
    const int l = t & 63;
    const int w = __builtin_amdgcn_readfirstlane(t >> 6);
    const int wr = w >> 1, wc = w & 1;
    const int li = l & 15, lg = l >> 4;
    const int lr = l >> 2;
    const int colu = (((l & 3) ^ (lr & 3)) << 3);   // inverse-swizzled src col
    const int swz = (li & 3) << 3;                   // read-side xor

    for (int k0 = 0; k0 < K; k0 += BK) {
        __syncthreads();
        #pragma unroll
        for (int it = 0; it < 2; ++it) {
            const int c2 = it * 4 + w;
            const int row = c2 * 16 + lr;
            glds16(&A[(size_t)(tileM + row) * K + k0 + colu], &As[c2 * 512]);
            glds16(&Bt[(size_t)(tileN + row) * K + k0 + colu], &Bs[c2 * 512]);
        }
        __syncthreads();
        bf16x8 a[4], b[4];
        #pragma unroll
        for (int m = 0; m < 4; ++m)
            a[m] = *(const bf16x8*)&As[(wr * 64 + m * 16 + li) * 32 + ((lg << 3) ^ swz)];
        #pragma unroll
        for (int n = 0; n < 4; ++n)
            b[n] = *(const bf16x8*)&Bs[(wc * 64 + n * 16 + li) * 32 + ((lg << 3) ^ swz)];
        #pragma unroll
        for (int m = 0; m < 4; ++m)
            #pragma unroll
            for (int n = 0; n < 4; ++n)
                acc[m][n] = __builtin_amdgcn_mfma_f32_16x16x32_bf16(a[m], b[n], acc[m][n], 0, 0, 0);
    }
}

// ---------------------------------------------------------------------------
// Output projection: ctx[M][D] * Wo^T + bo -> fp32 out. grid 256 flat,
// XCD swizzle. Direct stores.
// ---------------------------------------------------------------------------
__global__ __launch_bounds__(256) void out_gemm(const ushort* __restrict__ ctx,
                                                const ushort* __restrict__ Wt,
                                                const float* __restrict__ bo,
                                                float* __restrict__ outp) {
    __shared__ ushort As[128 * 32];
    __shared__ ushort Bs[128 * 32];
    f32x4 acc[4][4];
    #pragma unroll
    for (int m = 0; m < 4; ++m)
        #pragma unroll
        for (int n = 0; n < 4; ++n)
            acc[m][n] = (f32x4){0.f, 0.f, 0.f, 0.f};

    const int wg = (blockIdx.x & 7) * 32 + (blockIdx.x >> 3);  // XCD swizzle
    const int tileM = (wg & 31) * 128;
    const int tileN = (wg >> 5) * 128;
    const ushort* Bmat = Wt + (size_t)3 * D_ * D_;   // Wo^T

    gemm_tile(ctx, Bmat, D_, tileM, tileN, As, Bs, acc);

    const int l = threadIdx.x & 63, w = threadIdx.x >> 6;
    const int wr = w >> 1, wc = w & 1;
    const int li = l & 15, lg = l >> 4;
    #pragma unroll
    for (int n = 0; n < 4; ++n) {
        float bias = bo[tileN + wc * 64 + n * 16 + li];
        #pragma unroll
        for (int m = 0; m < 4; ++m)
            #pragma unroll
            for (int r = 0; r < 4; ++r) {
                int grow = tileM + wr * 64 + m * 16 + lg * 4 + r;
                int gcol = tileN + wc * 64 + n * 16 + li;
                outp[(size_t)grow * D_ + gcol] = acc[m][n][r] + bias;
            }
    }
}

// ---------------------------------------------------------------------------
// MFMA causal flash attention (R11 structure, unchanged): swapped-QK^T
// 16x16, dual q-tile per block (A: qt=p, B: qt=31-p share K/V tiles),
// fixed-scale softmax, lsum via MFMA-of-ones, Ps slot-XOR LDS,
// K/V [64][64] LDS dbuf, slot^(row&7) swizzle, 1 barrier/iter.
// grid 512 (16 pairs x 32 heads, XCD-swizzled).
// ---------------------------------------------------------------------------
__device__ __forceinline__ void qk_mfma(f32x4 st[4], const ushort* Kb,
                                        const bf16x8 bq[2],
                                        int li, int lg, int rswz) {
    #pragma unroll
    for (int c = 0; c < 4; ++c) {
        st[c] = (f32x4){0.f, 0.f, 0.f, 0.f};
        #pragma unroll
        for (int tk = 0; tk < 2; ++tk) {
            bf16x8 kf = *(const bf16x8*)&Kb[(c * 16 + li) * 64 + (((tk * 4 + lg) ^ rswz) * 8)];
            st[c] = __builtin_amdgcn_mfma_f32_16x16x32_bf16(kf, bq[tk], st[c], 0, 0, 0);
        }
    }
}

__device__ __forceinline__ void softmax_pv(f32x4 st[4], const ushort* Vb,
                                           bool masked, int jkb, int qg,
                                           int li, int lg, int rswz,
                                           ushort* PsW, f32x4& lacc,
                                           f32x4 od[4], bf16x8 ones) {
    if (masked) {
        #pragma unroll
        for (int c = 0; c < 4; ++c)
            #pragma unroll
            for (int r = 0; r < 4; ++r) {
                const int kgl = jkb * 64 + c * 16 + lg * 4 + r;
                if (kgl > qg) st[c][r] = -INFINITY;
            }
    }
    const int sw = li & 7;
    #pragma unroll
    for (int c = 0; c < 4; ++c) {
        float p0 = exp2f(st[c][0]);
        float p1 = exp2f(st[c][1]);
        float p2 = exp2f(st[c][2]);
        float p3 = exp2f(st[c][3]);
        uint32_t w0, w1;
        asm("v_cvt_pk_bf16_f32 %0, %1, %2" : "=v"(w0) : "v"(p0), "v"(p1));
        asm("v_cvt_pk_bf16_f32 %0, %1, %2" : "=v"(w1) : "v"(p2), "v"(p3));
        uint2 pk; pk.x = w0; pk.y = w1;
        *(uint2*)&PsW[li * 64 + (((c * 2 + (lg >> 1)) ^ sw) << 3) + ((lg & 1) << 2)] = pk;
    }
    #pragma unroll
    for (int tj = 0; tj < 2; ++tj) {
        bf16x8 pa = *(const bf16x8*)&PsW[li * 64 + (((tj * 4 + lg) ^ sw) << 3)];
        lacc = __builtin_amdgcn_mfma_f32_16x16x32_bf16(pa, ones, lacc, 0, 0, 0);
        #pragma unroll
        for (int db = 0; db < 4; ++db) {
            bf16x8 bv = *(const bf16x8*)&Vb[(db * 16 + li) * 64 + (((tj * 4 + lg) ^ rswz) * 8)];
            od[db] = __builtin_amdgcn_mfma_f32_16x16x32_bf16(pa, bv, od[db], 0, 0, 0);
        }
    }
}

__global__ __launch_bounds__(256, 2) void attn_fwd(const ushort* __restrict__ q,
                                                   const ushort* __restrict__ k,
                                                   const ushort* __restrict__ vt,
                                                   ushort* __restrict__ ctx) {
    __shared__ ushort Ks[2][4096];      // [buf][row*64 + slot*8], swizzled
    __shared__ ushort Vs[2][4096];
    __shared__ ushort Ps[4][1024];      // per-wave [16][64], slot-swizzled

    const int t = threadIdx.x;
    const int l = t & 63;
    const int w = __builtin_amdgcn_readfirstlane(t >> 6);
    const int li = l & 15, lg = l >> 4;
    const int f = blockIdx.x;                        // 0..511
    const int bh = ((f & 7) << 2) | ((f >> 3) & 3);  // XCD i owns heads 4i..4i+3
    const int p = f >> 5;                            // 0..15
    const int qtA = p, qtB = 31 - p;
    const int b = bh >> 4, h = bh & 15;

    const ushort* Qg = q + ((size_t)b * N_) * D_ + h * 64;
    const ushort* Kg = k + ((size_t)b * N_) * D_ + h * 64;
    const ushort* Vg = vt + (size_t)bh * HD_ * N_;
    ushort* PsW = &Ps[w][0];

    const int r8 = l >> 3;
    const int soff = ((l & 7) ^ r8) * 8;             // source slot offset
    const int rswz = li & 7;                         // read-side row xor

    const int qgA = qtA * 64 + w * 16 + li;
    const int qgB = qtB * 64 + w * 16 + li;

    bf16x8 bqA[2], bqB[2];
    #pragma unroll
    for (int tk = 0; tk < 2; ++tk) {
        bqA[tk] = *(const bf16x8*)&Qg[(size_t)qgA * D_ + tk * 32 + lg * 8];
        bqB[tk] = *(const bf16x8*)&Qg[(size_t)qgB * D_ + tk * 32 + lg * 8];
    }

    bf16x8 ones;
    #pragma unroll
    for (int i = 0; i < 8; ++i) ones[i] = (__bf16)1.0f;

    f32x4 odA[4], odB[4];
    #pragma unroll
    for (int db = 0; db < 4; ++db) {
        odA[db] = (f32x4){0.f, 0.f, 0.f, 0.f};
        odB[db] = (f32x4){0.f, 0.f, 0.f, 0.f};
    }
    f32x4 laccA = (f32x4){0.f, 0.f, 0.f, 0.f};
    f32x4 laccB = (f32x4){0.f, 0.f, 0.f, 0.f};

    #pragma unroll
    for (int i = 0; i < 2; ++i) {
        const int seg = w + i * 4;
        const int row = seg * 8 + r8;
        glds16(&Kg[(size_t)row * D_ + soff], &Ks[0][seg * 512]);
        glds16(&Vg[(size_t)row * N_ + soff], &Vs[0][seg * 512]);
    }
    __syncthreads();

    int cur = 0;
    for (int kb = 0; kb <= qtB; ++kb) {
        if (kb < qtB) {
            #pragma unroll
            for (int i = 0; i < 2; ++i) {
                const int seg = w + i * 4;
                const int row = seg * 8 + r8;
                glds16(&Kg[(size_t)((kb + 1) * 64 + row) * D_ + soff], &Ks[cur ^ 1][seg * 512]);
                glds16(&Vg[(size_t)row * N_ + (kb + 1) * 64 + soff], &Vs[cur ^ 1][seg * 512]);
            }
        }
        {
            f32x4 st[4];
            qk_mfma(st, Ks[cur], bqB, li, lg, rswz);
            softmax_pv(st, Vs[cur], kb == qtB, kb, qgB, li, lg, rswz, PsW, laccB, odB, ones);
        }
        if (kb <= qtA) {
            f32x4 st[4];
            qk_mfma(st, Ks[cur], bqA, li, lg, rswz);
            softmax_pv(st, Vs[cur], kb == qtA, kb, qgA, li, lg, rswz, PsW, laccA, odA, ones);
        }
        __syncthreads();
        cur ^= 1;
    }

    #pragma unroll
    for (int r = 0; r < 4; ++r) {
        const float invA = 1.f / laccA[r];
        const int growA = qtA * 64 + w * 16 + lg * 4 + r;
        #pragma unroll
        for (int db = 0; db < 4; ++db)
            ctx[((size_t)(b * N_ + growA)) * D_ + h * 64 + db * 16 + li] = bfbits(odA[db][r] * invA);
        const float invB = 1.f / laccB[r];
        const int growB = qtB * 64 + w * 16 + lg * 4 + r;
        #pragma unroll
        for (int db = 0; db < 4; ++db)
            ctx[((size_t)(b * N_ + growB)) * D_ + h * 64 + db * 16 + li] = bfbits(odB[db][r] * invB);
    }
}

// ---------------------------------------------------------------------------
extern "C" void kernel_launch(void* const* d_in, const int* in_sizes, int n_in,
                              void* d_out, int out_size, void* d_ws, size_t ws_size,
                              hipStream_t stream) {
    (void)in_sizes; (void)n_in; (void)out_size; (void)ws_size;
    const float* x  = (const float*)d_in[0];
    const float* Wq = (const float*)d_in[1];
    const float* Wk = (const float*)d_in[2];
    const float* Wv = (const float*)d_in[3];
    const float* Wo = (const float*)d_in[4];
    const float* bo = (const float*)d_in[5];
    float* outp = (float*)d_out;

    ushort* xb  = (ushort*)d_ws;                       //  8 MB [M][D]
    ushort* Wt  = xb + (size_t)M_ * D_;                //  8 MB (4x 1024^2, n-major)
    ushort* qb  = Wt + (size_t)4 * D_ * D_;            //  8 MB [M][D]
    ushort* kb  = qb + (size_t)M_ * D_;                //  8 MB [M][D]
    ushort* vtb = kb + (size_t)M_ * D_;                //  8 MB [B,H,HD,N] == [b*1024+d][N]
    ushort* ctx = vtb + (size_t)M_ * D_;               //  8 MB [M][D]

    prep<<<dim3(8192), 256, 0, stream>>>(x, Wq, Wk, Wv, Wo, xb, Wt);
    qkv8_gemm<<<dim3(192), 512, 0, stream>>>(xb, Wt, qb, kb, vtb);
    attn_fwd<<<dim3(512), 256, 0, stream>>>(qb, kb, vtb, ctx);
    out_gemm<<<dim3(256), 256, 0, stream>>>(ctx, Wt, bo, outp);
}